// Round 2
// baseline (1498.669 us; speedup 1.0000x reference)
//
#include <hip/hip_runtime.h>

// x is (32, 2048, 512) fp32. Outputs: res = x - ma, ma. Concatenated in d_out.
#define B_   32
#define T_   2048
#define C_   512
#define S_   (B_ * C_)               // 16384 independent series
#define NC_  64                      // chunks along time
#define L_   (T_ / NC_)              // 32 steps per chunk
#define GPC_ 16                      // blocks (series-groups) per chunk
#define NBLK_ (NC_ * GPC_)           // 1024 blocks
#define TOTAL_ ((size_t)B_ * T_ * C_)

// ---- constexpr 2x2 matrix power (double precision, compile-time) ----------
struct M2 { double m00, m01, m10, m11; };
constexpr M2 mmul(M2 a, M2 b) {
  return { a.m00*b.m00 + a.m01*b.m10, a.m00*b.m01 + a.m01*b.m11,
           a.m10*b.m00 + a.m11*b.m10, a.m10*b.m01 + a.m11*b.m11 };
}
constexpr M2 mpow(M2 a, int n) {
  M2 r{1.0, 0.0, 0.0, 1.0};
  for (int i = 0; i < n; ++i) r = mmul(r, a);
  return r;
}
constexpr double dALPHA = 0.3, dBETA = 0.3;
// state_t = M * state_{t-1} + (alpha, alpha*beta) * x_t
constexpr M2 M1{1.0 - dALPHA, 1.0 - dALPHA,
                -dALPHA * dBETA, dBETA * (1.0 - dALPHA) + (1.0 - dBETA)};
constexpr M2 ML = mpow(M1, L_);
constexpr float ML00 = (float)ML.m00, ML01 = (float)ML.m01;
constexpr float ML10 = (float)ML.m10, ML11 = (float)ML.m11;

// ---- recurrence step (matches reference arithmetic) -----------------------
__device__ __forceinline__ void step1(float& s, float& b, float x) {
  const float A = 0.3f, Bt = 0.3f;
  float sp = s;
  s = A * x + (1.0f - A) * (sp + b);
  b = Bt * (s - sp) + (1.0f - Bt) * b;
}
__device__ __forceinline__ void step4(float4& s, float4& b, const float4 x) {
  step1(s.x, b.x, x.x);
  step1(s.y, b.y, x.y);
  step1(s.z, b.z, x.z);
  step1(s.w, b.w, x.w);
}

// ---- agent-scope publish/read helpers (cross-XCD coherent) ----------------
__device__ __forceinline__ void publish2(float2* p, float sv, float bv) {
  union { float2 f; unsigned long long u; } w;
  w.f = make_float2(sv, bv);
  __hip_atomic_store((unsigned long long*)p, w.u,
                     __ATOMIC_RELAXED, __HIP_MEMORY_SCOPE_AGENT);
}
__device__ __forceinline__ float2 readagg(const float2* p) {
  union { float2 f; unsigned long long u; } w;
  w.u = __hip_atomic_load((const unsigned long long*)p,
                          __ATOMIC_RELAXED, __HIP_MEMORY_SCOPE_AGENT);
  return w.f;
}

// ---- prologue: zero flags + ticket (ws is poisoned 0xAA every launch) -----
__global__ void zero_ctrl(unsigned int* __restrict__ p, int n) {
  int i = blockIdx.x * 256 + threadIdx.x;
  if (i < n) p[i] = 0u;
}

// ---- fused single-pass DEMA: ticket-ordered decoupled chunk scan ----------
__global__ __launch_bounds__(256, 2) void dema_fused(
    const float* __restrict__ x, float* __restrict__ out,
    float2* __restrict__ stA, unsigned int* __restrict__ flags,
    unsigned int* __restrict__ ticket) {
  __shared__ unsigned int s_tau;
  if (threadIdx.x == 0) s_tau = atomicAdd(ticket, 1u);
  __syncthreads();
  const int tau = (int)s_tau;
  const int c = tau >> 4;                 // chunk index (0..63)
  const int g = tau & (GPC_ - 1);         // series group (0..15)
  const int q = g * 256 + (int)threadIdx.x;   // series-quad (0..4095)
  const int bb = q >> 7;                  // batch (C_/4 = 128 quads/row)
  const int ch = (q & 127) << 2;          // channel
  const size_t base = ((size_t)bb * T_ + (size_t)c * L_) * C_ + ch;
  const float4* xp = reinterpret_cast<const float4*>(x + base);
  const int STRD = C_ / 4;                // float4s between timesteps

  // Load this chunk's 32 timesteps into registers (32 loads in flight).
  float4 xv[L_];
  #pragma unroll
  for (int t = 0; t < L_; ++t) xv[t] = xp[(size_t)t * STRD];

  // Local scan -> aggregate. Chunk 0 uses the true init; others zero-init
  // (linear contribution).
  float4 s, b;
  if (c == 0) {
    s = xv[0];
    b = make_float4(xv[1].x - xv[0].x, xv[1].y - xv[0].y,
                    xv[1].z - xv[0].z, xv[1].w - xv[0].w);
    #pragma unroll
    for (int t = 1; t < L_; ++t) step4(s, b, xv[t]);
  } else {
    s = make_float4(0.f, 0.f, 0.f, 0.f);
    b = make_float4(0.f, 0.f, 0.f, 0.f);
    #pragma unroll
    for (int t = 0; t < L_; ++t) step4(s, b, xv[t]);
  }

  // Publish aggregate (4 series per thread), then raise this block's flag.
  float2* ap = stA + (size_t)c * S_ + (size_t)bb * C_ + ch;
  publish2(ap + 0, s.x, b.x);
  publish2(ap + 1, s.y, b.y);
  publish2(ap + 2, s.z, b.z);
  publish2(ap + 3, s.w, b.w);
  __syncthreads();                        // drains vmem before barrier
  if (threadIdx.x == 0) {
    __threadfence();
    __hip_atomic_store(&flags[tau], 1u, __ATOMIC_RELEASE,
                       __HIP_MEMORY_SCOPE_AGENT);
  }

  float4* resp = reinterpret_cast<float4*>(out + base);
  float4* map  = reinterpret_cast<float4*>(out + TOTAL_ + base);

  if (c == 0) {
    // Replay with true init; ma[0] = s0, res[0] = 0 exactly.
    s = xv[0];
    b = make_float4(xv[1].x - xv[0].x, xv[1].y - xv[0].y,
                    xv[1].z - xv[0].z, xv[1].w - xv[0].w);
    map[0]  = s;
    resp[0] = make_float4(0.f, 0.f, 0.f, 0.f);
    #pragma unroll
    for (int t = 1; t < L_; ++t) {
      float4 xt = xv[t];
      step4(s, b, xt);
      map[(size_t)t * STRD] = s;
      resp[(size_t)t * STRD] =
          make_float4(xt.x - s.x, xt.y - s.y, xt.z - s.z, xt.w - s.w);
    }
  } else {
    // Lookback: incoming(c) = sum_{j<c} ML^(c-1-j) * agg(j).
    // Deadlock-free: flag (j,g) belongs to a strictly lower ticket.
    float2 v0 = {0.f, 0.f}, v1 = {0.f, 0.f}, v2 = {0.f, 0.f}, v3 = {0.f, 0.f};
    float p00 = 1.f, p01 = 0.f, p10 = 0.f, p11 = 1.f;
    for (int j = c - 1; j >= 0; --j) {
      const unsigned int* f = &flags[(j << 4) | g];
      while (__hip_atomic_load(f, __ATOMIC_ACQUIRE,
                               __HIP_MEMORY_SCOPE_AGENT) == 0u)
        __builtin_amdgcn_s_sleep(4);
      const float2* jp = stA + (size_t)j * S_ + (size_t)bb * C_ + ch;
      float2 a0 = readagg(jp + 0);
      float2 a1 = readagg(jp + 1);
      float2 a2 = readagg(jp + 2);
      float2 a3 = readagg(jp + 3);
      v0.x += p00 * a0.x + p01 * a0.y;  v0.y += p10 * a0.x + p11 * a0.y;
      v1.x += p00 * a1.x + p01 * a1.y;  v1.y += p10 * a1.x + p11 * a1.y;
      v2.x += p00 * a2.x + p01 * a2.y;  v2.y += p10 * a2.x + p11 * a2.y;
      v3.x += p00 * a3.x + p01 * a3.y;  v3.y += p10 * a3.x + p11 * a3.y;
      // P <- ML * P (powers of one matrix commute; either order works)
      float n00 = ML00 * p00 + ML01 * p10, n01 = ML00 * p01 + ML01 * p11;
      float n10 = ML10 * p00 + ML11 * p10, n11 = ML10 * p01 + ML11 * p11;
      p00 = n00; p01 = n01; p10 = n10; p11 = n11;
    }
    s = make_float4(v0.x, v1.x, v2.x, v3.x);
    b = make_float4(v0.y, v1.y, v2.y, v3.y);
    #pragma unroll
    for (int t = 0; t < L_; ++t) {
      float4 xt = xv[t];
      step4(s, b, xt);
      map[(size_t)t * STRD] = s;
      resp[(size_t)t * STRD] =
          make_float4(xt.x - s.x, xt.y - s.y, xt.z - s.z, xt.w - s.w);
    }
  }
}

extern "C" void kernel_launch(void* const* d_in, const int* in_sizes, int n_in,
                              void* d_out, int out_size, void* d_ws, size_t ws_size,
                              hipStream_t stream) {
  const float* x = (const float*)d_in[0];
  float* out = (float*)d_out;
  // ws layout: stA (NC_*S_ float2 = 8 MB) | flags (NBLK_ u32) | ticket (u32)
  float2* stA = (float2*)d_ws;
  unsigned int* flags =
      (unsigned int*)((char*)d_ws + (size_t)NC_ * S_ * sizeof(float2));

  zero_ctrl<<<dim3((NBLK_ + 1 + 255) / 256), dim3(256), 0, stream>>>(
      flags, NBLK_ + 1);
  dema_fused<<<dim3(NBLK_), dim3(256), 0, stream>>>(
      x, out, stA, flags, flags + NBLK_);
}